// Round 8
// baseline (668.764 us; speedup 1.0000x reference)
//
#include <hip/hip_runtime.h>
#include <math.h>

#define N_NODES 100000
#define DIM 128
#define NREL 4
#define NEDGE 1600000
#define LN_EPS 1e-3f

#define NBUCK 196          // ceil(N_NODES/512) row-buckets of 512 rows
#define BCAP 10240         // capacity per (rel,bucket); mean 8192, sd ~90
#define P1_VPT 16
#define P1_EDGES 4096      // 256 * P1_VPT
#define BCNT_STRIDE 16     // one counter per 64B line (XCD atomic ping-pong fix)

typedef __attribute__((ext_vector_type(8))) short bf16x8;
typedef __attribute__((ext_vector_type(4))) float f32x4;

__device__ __forceinline__ float bf2f(unsigned short b) {
    return __uint_as_float(((unsigned int)b) << 16);
}
__device__ __forceinline__ unsigned short f2bf(float f) {
    unsigned int u = __float_as_uint(f);
    u += 0x7FFFu + ((u >> 16) & 1u);      // RN-even
    return (unsigned short)(u >> 16);
}

// ---------------------------------------------------------------------------
// Prep: bfr[r][d] = b_fuse[d] + sum_k rel[r][k]*W_fuse[D+k][d]; softmax(rel_w)
// ---------------------------------------------------------------------------
__global__ __launch_bounds__(512) void prep_kernel(
    const float* __restrict__ rel_emb, const float* __restrict__ W_fuse,
    const float* __restrict__ b_fuse, const float* __restrict__ rel_weights,
    float* __restrict__ bfr, float* __restrict__ wsm)
{
    int t = threadIdx.x;
    int r = t >> 7;
    int d = t & 127;
    float acc = b_fuse[d];
    for (int k = 0; k < DIM; ++k)
        acc += rel_emb[r * DIM + k] * W_fuse[(DIM + k) * DIM + d];
    bfr[r * DIM + d] = acc;
    if (t < NREL) {
        float m = rel_weights[0];
        for (int i = 1; i < NREL; ++i) m = fmaxf(m, rel_weights[i]);
        float s = 0.f;
        for (int i = 0; i < NREL; ++i) s += expf(rel_weights[i] - m);
        wsm[t] = expf(rel_weights[t] - m) / s;
    }
}

// ---------------------------------------------------------------------------
// Pack weights into MFMA B-fragment order, split hi/lo bf16.
// mat: 0=W_fuse[:128], 1..4=W_rel[r], 5=W_gate.
// ---------------------------------------------------------------------------
__global__ __launch_bounds__(256) void pack_kernel(
    const float* __restrict__ Wf, const float* __restrict__ Wr,
    const float* __restrict__ Wg,
    unsigned short* __restrict__ PH, unsigned short* __restrict__ PL)
{
    int mat = blockIdx.y;
    int idx = blockIdx.x * 256 + threadIdx.x;   // 0..16383
    int j = idx & 7;
    int lane = (idx >> 3) & 63;
    int ntile = (idx >> 9) & 7;
    int kblk = idx >> 12;
    int k = kblk * 32 + (lane >> 4) * 8 + j;
    int n = ntile * 16 + (lane & 15);
    const float* src = (mat == 0) ? Wf :
                       (mat == 5) ? Wg : (Wr + (size_t)(mat - 1) * DIM * DIM);
    float w = src[k * DIM + n];
    unsigned short hi = f2bf(w);
    float lo = w - bf2f(hi);
    PH[mat * 16384 + idx] = hi;
    PL[mat * 16384 + idx] = f2bf(lo);
}

// ---------------------------------------------------------------------------
// X (fp32) -> Xb (bf16)  [fallback path only]
// ---------------------------------------------------------------------------
__global__ __launch_bounds__(256) void xb_kernel(
    const float* __restrict__ X, unsigned short* __restrict__ Xb)
{
    int idx = blockIdx.x * 256 + threadIdx.x;   // N*DIM/4 exact
    float4 f = ((const float4*)X)[idx];
    ushort4 o;
    o.x = f2bf(f.x); o.y = f2bf(f.y); o.z = f2bf(f.z); o.w = f2bf(f.w);
    ((ushort4*)Xb)[idx] = o;
}

// ---------------------------------------------------------------------------
// Y = X @ W_fuse[:128]  (dense MFMA, hi/lo A and B, 3-pass) -> bf16 Yb.
// Yb layout is QUARTER-SPLIT: [4][N][32] (64B quarter-rows) so the gather's
// per-pass working set is 6.4MB vs 4MB/XCD L2 (R7: half-split 12.8MB gave
// hit 57->62%; quarter targets ~75%).
// ---------------------------------------------------------------------------
__global__ __launch_bounds__(256) void y_kernel(
    const float* __restrict__ X,
    const unsigned short* __restrict__ PH,
    const unsigned short* __restrict__ PL,
    unsigned short* __restrict__ Yb)
{
    __shared__ unsigned short sXh[32 * 128];
    __shared__ unsigned short sXl[32 * 128];

    int t = threadIdx.x;
    int row0 = blockIdx.x * 32;
    int wv = t >> 6, l = t & 63, lq = l >> 4, lm = l & 15;

    const float4* Xs = (const float4*)(X + (size_t)row0 * DIM);
#pragma unroll
    for (int it = 0; it < 2; ++it) {
        int i = t + it * 256;
        float4 f0 = Xs[2 * i];
        float4 f1 = Xs[2 * i + 1];
        float e[8] = {f0.x, f0.y, f0.z, f0.w, f1.x, f1.y, f1.z, f1.w};
        unsigned short h[8], lo[8];
#pragma unroll
        for (int j = 0; j < 8; ++j) {
            h[j] = f2bf(e[j]);
            lo[j] = f2bf(e[j] - bf2f(h[j]));
        }
        uint4 hv, lv;
        hv.x = ((unsigned int)h[1] << 16) | h[0];
        hv.y = ((unsigned int)h[3] << 16) | h[2];
        hv.z = ((unsigned int)h[5] << 16) | h[4];
        hv.w = ((unsigned int)h[7] << 16) | h[6];
        lv.x = ((unsigned int)lo[1] << 16) | lo[0];
        lv.y = ((unsigned int)lo[3] << 16) | lo[2];
        lv.z = ((unsigned int)lo[5] << 16) | lo[4];
        lv.w = ((unsigned int)lo[7] << 16) | lo[6];
        int row = i >> 4, ck = i & 15;
        int off = row * 256 + ((ck * 16) ^ ((row & 7) << 4));
        *(uint4*)((char*)sXh + off) = hv;
        *(uint4*)((char*)sXl + off) = lv;
    }
    __syncthreads();

    f32x4 acc[2][2];
#pragma unroll
    for (int mt = 0; mt < 2; ++mt)
#pragma unroll
        for (int ni = 0; ni < 2; ++ni)
#pragma unroll
            for (int r = 0; r < 4; ++r) acc[mt][ni][r] = 0.f;

#pragma unroll
    for (int kb = 0; kb < 4; ++kb) {
        int c0 = kb * 64 + lq * 16;
        int r0 = lm, r1 = 16 + lm;
        int o0 = r0 * 256 + (c0 ^ ((r0 & 7) << 4));
        int o1 = r1 * 256 + (c0 ^ ((r1 & 7) << 4));
        bf16x8 ah0 = *(const bf16x8*)((char*)sXh + o0);
        bf16x8 ah1 = *(const bf16x8*)((char*)sXh + o1);
        bf16x8 al0 = *(const bf16x8*)((char*)sXl + o0);
        bf16x8 al1 = *(const bf16x8*)((char*)sXl + o1);
#pragma unroll
        for (int ni = 0; ni < 2; ++ni) {
            int nt_ = wv * 2 + ni;
            int fi = ((kb * 8 + nt_) * 64 + l) << 3;
            bf16x8 bh = *(const bf16x8*)(PH + fi);
            bf16x8 bl = *(const bf16x8*)(PL + fi);
            acc[0][ni] = __builtin_amdgcn_mfma_f32_16x16x32_bf16(ah0, bh, acc[0][ni], 0, 0, 0);
            acc[1][ni] = __builtin_amdgcn_mfma_f32_16x16x32_bf16(ah1, bh, acc[1][ni], 0, 0, 0);
            acc[0][ni] = __builtin_amdgcn_mfma_f32_16x16x32_bf16(ah0, bl, acc[0][ni], 0, 0, 0);
            acc[1][ni] = __builtin_amdgcn_mfma_f32_16x16x32_bf16(ah1, bl, acc[1][ni], 0, 0, 0);
            acc[0][ni] = __builtin_amdgcn_mfma_f32_16x16x32_bf16(al0, bh, acc[0][ni], 0, 0, 0);
            acc[1][ni] = __builtin_amdgcn_mfma_f32_16x16x32_bf16(al1, bh, acc[1][ni], 0, 0, 0);
        }
    }
    __syncthreads();
#pragma unroll
    for (int mt = 0; mt < 2; ++mt)
#pragma unroll
    for (int ni = 0; ni < 2; ++ni) {
        int colg = (wv * 2 + ni) * 16 + lm;
#pragma unroll
        for (int r = 0; r < 4; ++r) {
            int row = mt * 16 + lq * 4 + r;
            sXh[row * 128 + colg] = f2bf(acc[mt][ni][r]);
        }
    }
    __syncthreads();
    // write out in [quarter][node][32] layout
    const uint4* s4 = (const uint4*)sXh;
#pragma unroll
    for (int it = 0; it < 2; ++it) {
        int i = t + it * 256;
        int row = i >> 4, ck = i & 15;
        int q = ck >> 2, c32 = ck & 3;         // 8-dim granule within quarter
        uint4* dst = (uint4*)(Yb + (size_t)q * N_NODES * 32 +
                              (size_t)(row0 + row) * 32);
        dst[c32] = s4[i];
    }
}

// ---------------------------------------------------------------------------
// binA: LDS-staged multisplit of edges into 196 row-buckets per relation.
// bcnt is line-padded (BCNT_STRIDE): 1 counter per 64B line to kill
// cross-XCD same-line atomic ping-pong.
// ---------------------------------------------------------------------------
__global__ __launch_bounds__(256) void binA_kernel(
    const int* __restrict__ arows, const int* __restrict__ acols,
    const float* __restrict__ avals,
    int* __restrict__ bcnt,                 // [NREL*NBUCK*BCNT_STRIDE], zeroed
    unsigned long long* __restrict__ edges2)
{
    __shared__ int hist[256];
    __shared__ int hoff[256];
    __shared__ int gbase[NBUCK];
    __shared__ unsigned long long stage[P1_EDGES];
    __shared__ unsigned short sbid[P1_EDGES];

    int t = threadIdx.x;
    int rl = blockIdx.y;
    int e0 = blockIdx.x * P1_EDGES;

    hist[t] = 0;
    __syncthreads();

    int b[P1_VPT], rank[P1_VPT], rloc[P1_VPT];
    unsigned int pay[P1_VPT];
#pragma unroll
    for (int i = 0; i < P1_VPT; ++i) {
        int e = e0 + i * 256 + t;
        b[i] = -1;
        if (e < NEDGE) {
            size_t off = (size_t)rl * NEDGE + e;
            int row = arows[off];
            unsigned int vb = __float_as_uint(avals[off]);
            vb += 0x7FFFu + ((vb >> 16) & 1u);      // RN-even to bf16
            pay[i] = ((unsigned int)acols[off] << 15) | ((vb >> 16) & 0x7FFFu);
            b[i] = row >> 9;
            rloc[i] = row & 511;
            rank[i] = atomicAdd(&hist[b[i]], 1);
        }
    }
    __syncthreads();

    // exclusive scan of hist -> hoff
    int v = hist[t];
    int run = v;
    hoff[t] = run;
    __syncthreads();
    for (int o = 1; o < 256; o <<= 1) {
        int other = (t >= o) ? hoff[t - o] : 0;
        __syncthreads();
        run += other;
        hoff[t] = run;
        __syncthreads();
    }
    hoff[t] = run - v;      // exclusive
    if (t < NBUCK) {
        int g = (v > 0) ? atomicAdd(&bcnt[(rl * NBUCK + t) * BCNT_STRIDE], v) : 0;
        gbase[t] = (rl * NBUCK + t) * BCAP + g;
    }
    __syncthreads();

#pragma unroll
    for (int i = 0; i < P1_VPT; ++i) {
        if (b[i] >= 0) {
            int slot = hoff[b[i]] + rank[i];
            stage[slot] = ((unsigned long long)rloc[i] << 32) | pay[i];
            sbid[slot] = (unsigned short)b[i];
        }
    }
    __syncthreads();

    int total = hoff[NBUCK - 1] + hist[NBUCK - 1];
    for (int idx = t; idx < total; idx += 256) {
        int bb = sbid[idx];
        int gaddr = gbase[bb] + (idx - hoff[bb]);
        if (gaddr - (rl * NBUCK + bb) * BCAP < BCAP)
            edges2[gaddr] = stage[idx];
    }
}

// ---------------------------------------------------------------------------
// bscan: exclusive scan of the 784 bucket counts -> bstart[784]
// ---------------------------------------------------------------------------
__global__ __launch_bounds__(1024) void bscan_kernel(
    const int* __restrict__ bcnt, int* __restrict__ bstart)
{
    __shared__ int s[1024];
    int t = threadIdx.x;
    int v = (t < NREL * NBUCK) ? min(bcnt[t * BCNT_STRIDE], BCAP) : 0;
    int run = v;
    s[t] = run;
    __syncthreads();
    for (int o = 1; o < 1024; o <<= 1) {
        int other = (t >= o) ? s[t - o] : 0;
        __syncthreads();
        run += other;
        s[t] = run;
        __syncthreads();
    }
    if (t < NREL * NBUCK) bstart[t] = run - v;
}

// ---------------------------------------------------------------------------
// binB: per (bucket, relation): LDS-hist 512 rows -> CSR starts + scatter.
// ---------------------------------------------------------------------------
__global__ __launch_bounds__(256) void binB_kernel(
    const unsigned long long* __restrict__ edges2,
    const int* __restrict__ bcnt, const int* __restrict__ bstart,
    int* __restrict__ rowstart, unsigned int* __restrict__ edges)
{
    __shared__ int rcnt[512];
    __shared__ int rpos[512];
    __shared__ int sc[256];

    int t = threadIdx.x;
    int b = blockIdx.x, rl = blockIdx.y;
    int gb = rl * NBUCK + b;
    int cnt = min(bcnt[gb * BCNT_STRIDE], BCAP);
    const unsigned long long* src = edges2 + (size_t)gb * BCAP;
    int row0 = b << 9;
    int nrows = min(512, N_NODES - row0);

    rcnt[t] = 0; rcnt[t + 256] = 0;
    __syncthreads();
    for (int e = t; e < cnt; e += 256)
        atomicAdd(&rcnt[(int)(src[e] >> 32)], 1);
    __syncthreads();

    int v0 = rcnt[2 * t], v1 = rcnt[2 * t + 1];
    int tsum = v0 + v1;
    int run = tsum;
    sc[t] = run;
    __syncthreads();
    for (int o = 1; o < 256; o <<= 1) {
        int other = (t >= o) ? sc[t - o] : 0;
        __syncthreads();
        run += other;
        sc[t] = run;
        __syncthreads();
    }
    int base = bstart[gb];
    int excl = base + run - tsum;
    rpos[2 * t] = excl;
    rpos[2 * t + 1] = excl + v0;
    __syncthreads();

    for (int i = t; i < nrows; i += 256)
        rowstart[rl * N_NODES + row0 + i] = rpos[i];
    __syncthreads();

    for (int e = t; e < cnt; e += 256) {
        unsigned long long s = src[e];
        int p = atomicAdd(&rpos[(int)(s >> 32)], 1);
        edges[p] = (unsigned int)s;
    }
}

// ---------------------------------------------------------------------------
// Gather over quarter-split Yb[4][N][32]: grid.y = (q<<2)|rel. 4-lane groups,
// each lane owns 8 dims of the 32-dim quarter (16B uint4 per edge). 4-deep
// pipeline. Per-lane compute/bytes identical to the half version; per-pass
// working set 6.4MB (vs 12.8 in R7: hit 62% -> predicted ~75%).
// ---------------------------------------------------------------------------
#define FMA8(acc, v, q)                                    \
    acc[0] += v * __uint_as_float((q).x << 16);            \
    acc[1] += v * __uint_as_float((q).x & 0xFFFF0000u);    \
    acc[2] += v * __uint_as_float((q).y << 16);            \
    acc[3] += v * __uint_as_float((q).y & 0xFFFF0000u);    \
    acc[4] += v * __uint_as_float((q).z << 16);            \
    acc[5] += v * __uint_as_float((q).z & 0xFFFF0000u);    \
    acc[6] += v * __uint_as_float((q).w << 16);            \
    acc[7] += v * __uint_as_float((q).w & 0xFFFF0000u);

__global__ __launch_bounds__(256) void gather_kernel(
    const unsigned short* __restrict__ Yb,   // [4][N][32]
    const int* __restrict__ rowstart,        // CSR starts, [NREL*N_NODES]
    const unsigned int* __restrict__ edges,
    const float* __restrict__ bfr,
    unsigned short* __restrict__ msgs)       // [R][N][128] bf16 (relu'd)
{
    int t = threadIdx.x;
    int grp = t >> 2, lane = t & 3;          // 64 groups x 4 lanes
    int row = blockIdx.x * 64 + grp;
    if (row >= N_NODES) return;
    int rl = blockIdx.y & 3;
    int q  = blockIdx.y >> 2;
    int g = rl * N_NODES + row;
    int s = rowstart[g];
    int e = (g == NREL * N_NODES - 1) ? (NREL * NEDGE) : rowstart[g + 1];

    float a0[8], a1[8], a2[8], a3[8];
#pragma unroll
    for (int i = 0; i < 8; ++i) { a0[i] = 0.f; a1[i] = 0.f; a2[i] = 0.f; a3[i] = 0.f; }

    const uint4* Yb4 = (const uint4*)(Yb + (size_t)q * N_NODES * 32);
    int ee = s;
    int nrem = e - s;
    if (nrem >= 4) {
        unsigned int p0 = edges[ee], p1 = edges[ee + 1],
                     p2 = edges[ee + 2], p3 = edges[ee + 3];
        while (nrem >= 4) {
            uint4 q0 = Yb4[((size_t)(p0 >> 15) << 2) + lane];
            uint4 q1 = Yb4[((size_t)(p1 >> 15) << 2) + lane];
            uint4 q2 = Yb4[((size_t)(p2 >> 15) << 2) + lane];
            uint4 q3 = Yb4[((size_t)(p3 >> 15) << 2) + lane];
            float v0 = __uint_as_float((p0 & 0x7FFFu) << 16);
            float v1 = __uint_as_float((p1 & 0x7FFFu) << 16);
            float v2 = __uint_as_float((p2 & 0x7FFFu) << 16);
            float v3 = __uint_as_float((p3 & 0x7FFFu) << 16);
            nrem -= 4; ee += 4;
            if (nrem >= 4) {       // prefetch next edge words under the FMAs
                p0 = edges[ee + 0]; p1 = edges[ee + 1];
                p2 = edges[ee + 2]; p3 = edges[ee + 3];
            }
            FMA8(a0, v0, q0)
            FMA8(a1, v1, q1)
            FMA8(a2, v2, q2)
            FMA8(a3, v3, q3)
        }
    }
    while (nrem > 0) {
        unsigned int p = edges[ee];
        uint4 qq = Yb4[((size_t)(p >> 15) << 2) + lane];
        float v = __uint_as_float((p & 0x7FFFu) << 16);
        FMA8(a0, v, qq)
        ++ee; --nrem;
    }
#pragma unroll
    for (int i = 0; i < 8; ++i) a0[i] += a1[i] + a2[i] + a3[i];

    // fused epilogue: + bfr, relu, bf16  (this pass owns dims q*32+lane*8..+8)
    const float4* bb = (const float4*)(bfr + rl * DIM + q * 32 + lane * 8);
    float4 b0 = bb[0], b1 = bb[1];
    float f0 = fmaxf(a0[0] + b0.x, 0.f), f1 = fmaxf(a0[1] + b0.y, 0.f);
    float f2 = fmaxf(a0[2] + b0.z, 0.f), f3 = fmaxf(a0[3] + b0.w, 0.f);
    float f4 = fmaxf(a0[4] + b1.x, 0.f), f5 = fmaxf(a0[5] + b1.y, 0.f);
    float f6 = fmaxf(a0[6] + b1.z, 0.f), f7 = fmaxf(a0[7] + b1.w, 0.f);
    uint4 o;
    o.x = ((unsigned int)f2bf(f1) << 16) | f2bf(f0);
    o.y = ((unsigned int)f2bf(f3) << 16) | f2bf(f2);
    o.z = ((unsigned int)f2bf(f5) << 16) | f2bf(f4);
    o.w = ((unsigned int)f2bf(f7) << 16) | f2bf(f6);
    ((uint4*)(msgs + ((size_t)g << 7) + q * 32))[lane] = o;
}

// ---------------------------------------------------------------------------
// gemm2: per 32-row tile: for rl: stage relu'd msgs -> GEMM2 (2-pass, B hi/lo),
// comb in regs; then gate GEMM from X (fp32->bf16 in-kernel), residual + LN.
// ---------------------------------------------------------------------------
__global__ __launch_bounds__(256) void gemm2_kernel(
    const unsigned short* __restrict__ msgs,
    const float* __restrict__ X,
    const unsigned short* __restrict__ PH,
    const unsigned short* __restrict__ PL,
    const float* __restrict__ br,
    const float* __restrict__ wsm,
    const float* __restrict__ bg,
    const float* __restrict__ gamma,
    const float* __restrict__ beta,
    float* __restrict__ out)
{
    __shared__ float sX[32 * 132];          // LN buffer; first 8KB doubles as sB
    __shared__ float red[32][8], red2[32][8];
    __shared__ float smu[32], srs[32];
    unsigned short* sB = (unsigned short*)sX;

    int t = threadIdx.x;
    int row0 = blockIdx.x * 32;
    int wv = t >> 6, l = t & 63, lq = l >> 4, lm = l & 15;

    f32x4 comb[2][2];
#pragma unroll
    for (int mt = 0; mt < 2; ++mt)
#pragma unroll
        for (int ni = 0; ni < 2; ++ni)
#pragma unroll
            for (int r = 0; r < 4; ++r) comb[mt][ni][r] = 0.f;

    // prologue: stage regs for rl=0
    uint4 m0, m1;
    {
        const uint4* src = (const uint4*)msgs + ((size_t)row0 << 4);
        m0 = src[t]; m1 = src[t + 256];
    }
    float4 xa, xb_, xc, xd;   // X gate tile staged regs (loaded during rl=3)

    for (int rl = 0; rl < NREL; ++rl) {
        __syncthreads();       // sB free (prev GEMM2 A-reads done)
        {
            int i0 = t, i1 = t + 256;
            int row = i0 >> 4, ck = i0 & 15;
            *(uint4*)((char*)sB + row * 256 + ((ck * 16) ^ ((row & 7) << 4))) = m0;
            row = i1 >> 4; ck = i1 & 15;
            *(uint4*)((char*)sB + row * 256 + ((ck * 16) ^ ((row & 7) << 4))) = m1;
        }
        if (rl < NREL - 1) {   // T14: issue next-tile loads, land after GEMM2
            const uint4* src = (const uint4*)msgs +
                ((size_t)((rl + 1) * N_NODES + row0) << 4);
            m0 = src[t]; m1 = src[t + 256];
        } else {
            const float4* Xs = (const float4*)(X + (size_t)row0 * DIM);
            xa = Xs[2 * t];       xb_ = Xs[2 * t + 1];
            xc = Xs[2 * (t + 256)]; xd = Xs[2 * (t + 256) + 1];
        }
        __syncthreads();       // sB ready

        const unsigned short* ph2 = PH + (size_t)(1 + rl) * 16384;
        const unsigned short* pl2 = PL + (size_t)(1 + rl) * 16384;
        f32x4 acc[2][2];
#pragma unroll
        for (int mt = 0; mt < 2; ++mt)
#pragma unroll
            for (int ni = 0; ni < 2; ++ni)
#pragma unroll
                for (int r = 0; r < 4; ++r) acc[mt][ni][r] = 0.f;

#pragma unroll
        for (int kb = 0; kb < 4; ++kb) {
            int c0 = kb * 64 + lq * 16;
            int r0 = lm, r1 = 16 + lm;
            int o0 = r0 * 256 + (c0 ^ ((r0 & 7) << 4));
            int o1 = r1 * 256 + (c0 ^ ((r1 & 7) << 4));
            bf16x8 a0v = *(const bf16x8*)((char*)sB + o0);
            bf16x8 a1v = *(const bf16x8*)((char*)sB + o1);
#pragma unroll
            for (int ni = 0; ni < 2; ++ni) {
                int nt_ = wv * 2 + ni;
                int fi = ((kb * 8 + nt_) * 64 + l) << 3;
                bf16x8 bh = *(const bf16x8*)(ph2 + fi);
                bf16x8 bl = *(const bf16x8*)(pl2 + fi);
                acc[0][ni] = __builtin_amdgcn_mfma_f32_16x16x32_bf16(a0v, bh, acc[0][ni], 0, 0, 0);
                acc[1][ni] = __builtin_amdgcn_mfma_f32_16x16x32_bf16(a1v, bh, acc[1][ni], 0, 0, 0);
                acc[0][ni] = __builtin_amdgcn_mfma_f32_16x16x32_bf16(a0v, bl, acc[0][ni], 0, 0, 0);
                acc[1][ni] = __builtin_amdgcn_mfma_f32_16x16x32_bf16(a1v, bl, acc[1][ni], 0, 0, 0);
            }
        }
        {
            float wr_ = wsm[rl];
#pragma unroll
            for (int mt = 0; mt < 2; ++mt)
#pragma unroll
            for (int ni = 0; ni < 2; ++ni) {
                int colg = (wv * 2 + ni) * 16 + lm;
                float b = br[rl * DIM + colg];
#pragma unroll
                for (int r = 0; r < 4; ++r)
                    comb[mt][ni][r] += wr_ * (acc[mt][ni][r] + b);
            }
        }
    }

    // ---- gate: stage X (hi-bf16) into sB
    __syncthreads();
    {
        float e0[8] = {xa.x, xa.y, xa.z, xa.w, xb_.x, xb_.y, xb_.z, xb_.w};
        uint4 hv;
        hv.x = ((unsigned int)f2bf(e0[1]) << 16) | f2bf(e0[0]);
        hv.y = ((unsigned int)f2bf(e0[3]) << 16) | f2bf(e0[2]);
        hv.z = ((unsigned int)f2bf(e0[5]) << 16) | f2bf(e0[4]);
        hv.w = ((unsigned int)f2bf(e0[7]) << 16) | f2bf(e0[6]);
        int i = t, row = i >> 4, ck = i & 15;
        *(uint4*)((char*)sB + row * 256 + ((ck * 16) ^ ((row & 7) << 4))) = hv;
        float e1[8] = {xc.x, xc.y, xc.z, xc.w, xd.x, xd.y, xd.z, xd.w};
        hv.x = ((unsigned int)f2bf(e1[1]) << 16) | f2bf(e1[0]);
        hv.y = ((unsigned int)f2bf(e1[3]) << 16) | f2bf(e1[2]);
        hv.z = ((unsigned int)f2bf(e1[5]) << 16) | f2bf(e1[4]);
        hv.w = ((unsigned int)f2bf(e1[7]) << 16) | f2bf(e1[6]);
        i = t + 256; row = i >> 4; ck = i & 15;
        *(uint4*)((char*)sB + row * 256 + ((ck * 16) ^ ((row & 7) << 4))) = hv;
    }
    __syncthreads();

    f32x4 accg[2][2];
#pragma unroll
    for (int mt = 0; mt < 2; ++mt)
#pragma unroll
        for (int ni = 0; ni < 2; ++ni)
#pragma unroll
            for (int r = 0; r < 4; ++r) accg[mt][ni][r] = 0.f;

    const unsigned short* phg = PH + (size_t)5 * 16384;
    const unsigned short* plg = PL + (size_t)5 * 16384;
#pragma unroll
    for (int kb = 0; kb < 4; ++kb) {
        int c0 = kb * 64 + lq * 16;
        int r0 = lm, r1 = 16 + lm;
        bf16x8 a0v = *(const bf16x8*)((char*)sB + r0 * 256 + (c0 ^ ((r0 & 7) << 4)));
        bf16x8 a1v = *(const bf16x8*)((char*)sB + r1 * 256 + (c0 ^ ((r1 & 7) << 4)));
#pragma unroll
        for (int ni = 0; ni < 2; ++ni) {
            int nt_ = wv * 2 + ni;
            int fi = ((kb * 8 + nt_) * 64 + l) << 3;
            bf16x8 bh = *(const bf16x8*)(phg + fi);
            bf16x8 bl = *(const bf16x8*)(plg + fi);
            accg[0][ni] = __builtin_amdgcn_mfma_f32_16x16x32_bf16(a0v, bh, accg[0][ni], 0, 0, 0);
            accg[1][ni] = __builtin_amdgcn_mfma_f32_16x16x32_bf16(a1v, bh, accg[1][ni], 0, 0, 0);
            accg[0][ni] = __builtin_amdgcn_mfma_f32_16x16x32_bf16(a0v, bl, accg[0][ni], 0, 0, 0);
            accg[1][ni] = __builtin_amdgcn_mfma_f32_16x16x32_bf16(a1v, bl, accg[1][ni], 0, 0, 0);
        }
    }
    __syncthreads();   // all sB ds_reads done; sX may overwrite

    // ---- stage the fp32 X tile (already in regs) into sX linear
    {
        int i = t, row = i >> 4, c = (i & 15) << 3;
        *(float4*)&sX[row * 132 + c] = xa;
        *(float4*)&sX[row * 132 + c + 4] = xb_;
        i = t + 256; row = i >> 4; c = (i & 15) << 3;
        *(float4*)&sX[row * 132 + c] = xc;
        *(float4*)&sX[row * 132 + c + 4] = xd;
    }
    __syncthreads();

    // ---- x = X + sigmoid(gate)*comb, in place in sX
#pragma unroll
    for (int mt = 0; mt < 2; ++mt)
#pragma unroll
    for (int ni = 0; ni < 2; ++ni) {
        int colg = (wv * 2 + ni) * 16 + lm;
        float bgv = bg[colg];
#pragma unroll
        for (int r = 0; r < 4; ++r) {
            int row = mt * 16 + lq * 4 + r;
            float g = 1.f / (1.f + expf(-(accg[mt][ni][r] + bgv)));
            sX[row * 132 + colg] += g * comb[mt][ni][r];
        }
    }
    __syncthreads();

    // ---- LayerNorm
    {
        int row = t >> 3, seg = t & 7;
        float s = 0.f, s2 = 0.f;
#pragma unroll
        for (int i = 0; i < 16; ++i) {
            float v = sX[row * 132 + seg * 16 + i];
            s += v; s2 += v * v;
        }
        red[row][seg] = s;
        red2[row][seg] = s2;
    }
    __syncthreads();
    if ((t & 7) == 0) {
        int row = t >> 3;
        float ts = 0.f, ts2 = 0.f;
#pragma unroll
        for (int i = 0; i < 8; ++i) { ts += red[row][i]; ts2 += red2[row][i]; }
        float mu = ts / DIM;
        float var = ts2 / DIM - mu * mu;
        smu[row] = mu;
        srs[row] = rsqrtf(var + LN_EPS);
    }
    __syncthreads();
    {
        float gm0 = gamma[l], gm1 = gamma[l + 64];
        float bt0 = beta[l],  bt1 = beta[l + 64];
#pragma unroll
        for (int rr = 0; rr < 8; ++rr) {
            int row = wv * 8 + rr;
            size_t gi = (size_t)(row0 + row) * DIM + l;
            out[gi]      = (sX[row * 132 + l]      - smu[row]) * srs[row] * gm0 + bt0;
            out[gi + 64] = (sX[row * 132 + l + 64] - smu[row]) * srs[row] * gm1 + bt1;
        }
    }
}

// ---------------------------------------------------------------------------
// FALLBACK path kernels (only if ws too small): old CSR build + fused mega
// ---------------------------------------------------------------------------
__global__ __launch_bounds__(256) void hist_kernel(
    const int* __restrict__ arows, int* __restrict__ counts)
{
    int e = blockIdx.x * 256 + threadIdx.x;
    int rl = blockIdx.y;
    if (e < NEDGE) {
        int row = arows[(size_t)rl * NEDGE + e];
        atomicAdd(&counts[rl * N_NODES + row], 1);
    }
}

__global__ __launch_bounds__(256) void scan1_kernel(
    int* __restrict__ counts, int* __restrict__ chunksums, int M)
{
    __shared__ int s[256];
    int chunk = blockIdx.x, t = threadIdx.x;
    int base = chunk * 1024 + t * 4;
    int v0 = (base + 0 < M) ? counts[base + 0] : 0;
    int v1 = (base + 1 < M) ? counts[base + 1] : 0;
    int v2 = (base + 2 < M) ? counts[base + 2] : 0;
    int v3 = (base + 3 < M) ? counts[base + 3] : 0;
    int p1 = v0, p2 = v0 + v1, p3 = v0 + v1 + v2, tsum = p3 + v3;
    int run = tsum;
    s[t] = run;
    __syncthreads();
    for (int off = 1; off < 256; off <<= 1) {
        int other = (t >= off) ? s[t - off] : 0;
        __syncthreads();
        run += other;
        s[t] = run;
        __syncthreads();
    }
    int excl = run - tsum;
    if (t == 255) chunksums[chunk] = run;
    if (base + 0 < M) counts[base + 0] = excl;
    if (base + 1 < M) counts[base + 1] = excl + p1;
    if (base + 2 < M) counts[base + 2] = excl + p2;
    if (base + 3 < M) counts[base + 3] = excl + p3;
}

__global__ __launch_bounds__(512) void scan2_kernel(
    int* __restrict__ chunksums, int nchunks)
{
    __shared__ int s[512];
    int t = threadIdx.x;
    int v = (t < nchunks) ? chunksums[t] : 0;
    int run = v;
    s[t] = run;
    __syncthreads();
    for (int off = 1; off < 512; off <<= 1) {
        int other = (t >= off) ? s[t - off] : 0;
        __syncthreads();
        run += other;
        s[t] = run;
        __syncthreads();
    }
    if (t < nchunks) chunksums[t] = run - v;
}

__global__ __launch_bounds__(256) void reorder_kernel(
    const int* __restrict__ arows, const int* __restrict__ acols,
    const float* __restrict__ avals,
    int* __restrict__ counts, const int* __restrict__ chunks,
    unsigned int* __restrict__ edges)
{
    int e = blockIdx.x * 256 + threadIdx.x;
    int rl = blockIdx.y;
    if (e < NEDGE) {
        size_t off = (size_t)rl * NEDGE + e;
        int row = arows[off];
        int g = rl * N_NODES + row;
        int pos = atomicAdd(&counts[g], 1) + chunks[g >> 10];
        unsigned int vb = __float_as_uint(avals[off]);
        vb += 0x7FFFu + ((vb >> 16) & 1u);
        edges[pos] = ((unsigned int)acols[off] << 15) | ((vb >> 16) & 0x7FFFu);
    }
}

__global__ __launch_bounds__(256) void mega_kernel(
    const unsigned short* __restrict__ Xb,
    const float* __restrict__ X,
    const int* __restrict__ counts,
    const int* __restrict__ chunks,
    const unsigned int* __restrict__ edges,
    const float* __restrict__ W1,
    const float* __restrict__ bfr,
    const float* __restrict__ Wr,
    const float* __restrict__ br,
    const float* __restrict__ wsm,
    const float* __restrict__ Wg,
    const float* __restrict__ bg,
    const float* __restrict__ gamma,
    const float* __restrict__ beta,
    float* __restrict__ out)
{
    __shared__ float sIn[32][DIM];
    __shared__ float red[32][8], red2[32][8];
    __shared__ float smu[32], srs[32];

    int t = threadIdx.x;
    int row0 = blockIdx.x * 32;
    int w = t >> 6;
    int l = t & 63;
    int grp = t >> 5, lane = t & 31;

    float comb_acc[8][2];
#pragma unroll
    for (int rr = 0; rr < 8; ++rr) { comb_acc[rr][0] = 0.f; comb_acc[rr][1] = 0.f; }

    for (int rl = 0; rl < NREL; ++rl) {
        __syncthreads();
#pragma unroll
        for (int i = 0; i < 4; ++i) {
            int ln = grp * 4 + i;
            int g = rl * N_NODES + row0 + ln;
            int s = (g == 0) ? 0 : counts[g - 1] + chunks[(g - 1) >> 10];
            int e = counts[g] + chunks[g >> 10];
            float4 a0 = make_float4(0.f, 0.f, 0.f, 0.f);
            int ee = s;
            for (; ee < e; ++ee) {
                unsigned int p0 = edges[ee];
                const ushort4* x0 = (const ushort4*)(Xb + ((size_t)(p0 >> 15) << 7));
                ushort4 q0 = x0[lane];
                float v0 = __uint_as_float((p0 & 0x7FFFu) << 16);
                a0.x += v0 * bf2f(q0.x); a0.y += v0 * bf2f(q0.y);
                a0.z += v0 * bf2f(q0.z); a0.w += v0 * bf2f(q0.w);
            }
            ((float4*)&sIn[ln][0])[lane] = a0;
        }
        __syncthreads();

        float acc1[8][2];
#pragma unroll
        for (int rr = 0; rr < 8; ++rr) { acc1[rr][0] = 0.f; acc1[rr][1] = 0.f; }
        for (int k4 = 0; k4 < DIM / 4; ++k4) {
            float wa[4], wb4[4];
#pragma unroll
            for (int j = 0; j < 4; ++j) {
                wa[j]  = W1[(k4 * 4 + j) * DIM + l];
                wb4[j] = W1[(k4 * 4 + j) * DIM + l + 64];
            }
#pragma unroll
            for (int rr = 0; rr < 8; ++rr) {
                float4 m = *(const float4*)&sIn[w * 8 + rr][k4 * 4];
                acc1[rr][0] += m.x * wa[0]  + m.y * wa[1]  + m.z * wa[2]  + m.w * wa[3];
                acc1[rr][1] += m.x * wb4[0] + m.y * wb4[1] + m.z * wb4[2] + m.w * wb4[3];
            }
        }
        __syncthreads();
        {
            float b0 = bfr[rl * DIM + l], b1 = bfr[rl * DIM + l + 64];
#pragma unroll
            for (int rr = 0; rr < 8; ++rr) {
                sIn[w * 8 + rr][l]      = fmaxf(acc1[rr][0] + b0, 0.f);
                sIn[w * 8 + rr][l + 64] = fmaxf(acc1[rr][1] + b1, 0.f);
            }
        }
        __syncthreads();

        const float* W2 = Wr + (size_t)rl * DIM * DIM;
        float acc2[8][2];
#pragma unroll
        for (int rr = 0; rr < 8; ++rr) { acc2[rr][0] = 0.f; acc2[rr][1] = 0.f; }
        for (int k4 = 0; k4 < DIM / 4; ++k4) {
            float wa[4], wb4[4];
#pragma unroll
            for (int j = 0; j < 4; ++j) {
                wa[j]  = W2[(k4 * 4 + j) * DIM + l];
                wb4[j] = W2[(k4 * 4 + j) * DIM + l + 64];
            }
#pragma unroll
            for (int rr = 0; rr < 8; ++rr) {
                float4 m = *(const float4*)&sIn[w * 8 + rr][k4 * 4];
                acc2[rr][0] += m.x * wa[0]  + m.y * wa[1]  + m.z * wa[2]  + m.w * wa[3];
                acc2[rr][1] += m.x * wb4[0] + m.y * wb4[1] + m.z * wb4[2] + m.w * wb4[3];
            }
        }
        {
            float wr_ = wsm[rl];
            float bb0 = br[rl * DIM + l], bb1 = br[rl * DIM + l + 64];
#pragma unroll
            for (int rr = 0; rr < 8; ++rr) {
                comb_acc[rr][0] += wr_ * (acc2[rr][0] + bb0);
                comb_acc[rr][1] += wr_ * (acc2[rr][1] + bb1);
            }
        }
    }

    __syncthreads();
    {
        const float4* src = (const float4*)(X + (size_t)row0 * DIM);
        float4* dst = (float4*)&sIn[0][0];
        for (int i = t; i < 32 * DIM / 4; i += 256) dst[i] = src[i];
    }
    __syncthreads();

    float accg[8][2];
#pragma unroll
    for (int rr = 0; rr < 8; ++rr) { accg[rr][0] = 0.f; accg[rr][1] = 0.f; }
    for (int k4 = 0; k4 < DIM / 4; ++k4) {
        float wa[4], wb4[4];
#pragma unroll
        for (int j = 0; j < 4; ++j) {
            wa[j]  = Wg[(k4 * 4 + j) * DIM + l];
            wb4[j] = Wg[(k4 * 4 + j) * DIM + l + 64];
        }
#pragma unroll
        for (int rr = 0; rr < 8; ++rr) {
            float4 m = *(const float4*)&sIn[w * 8 + rr][k4 * 4];
            accg[rr][0] += m.x * wa[0]  + m.y * wa[1]  + m.z * wa[2]  + m.w * wa[3];
            accg[rr][1] += m.x * wb4[0] + m.y * wb4[1] + m.z * wb4[2] + m.w * wb4[3];
        }
    }
    float xv[8][2];
    {
        float bg0 = bg[l], bg1 = bg[l + 64];
#pragma unroll
        for (int rr = 0; rr < 8; ++rr) {
            int row = w * 8 + rr;
            float g0 = 1.f / (1.f + expf(-(accg[rr][0] + bg0)));
            float g1 = 1.f / (1.f + expf(-(accg[rr][1] + bg1)));
            xv[rr][0] = sIn[row][l]      + g0 * comb_acc[rr][0];
            xv[rr][1] = sIn[row][l + 64] + g1 * comb_acc[rr][1];
        }
    }
    __syncthreads();
#pragma unroll
    for (int rr = 0; rr < 8; ++rr) {
        sIn[w * 8 + rr][l]      = xv[rr][0];
        sIn[w * 8 + rr][l + 64] = xv[rr][1];
    }
    __syncthreads();

    {
        int row = t >> 3, seg = t & 7;
        float s = 0.f, s2 = 0.f;
#pragma unroll
        for (int i = 0; i < 16; ++i) {
            float v = sIn[row][seg * 16 + i];
            s += v; s2 += v * v;
        }
        red[row][seg] = s;
        red2[row][seg] = s2;
    }
    __syncthreads();
    if ((t & 7) == 0) {
        int row = t >> 3;
        float ts = 0.f, ts2 = 0.f;
#pragma unroll
        for (int i = 0; i < 8; ++i) { ts += red[row][i]; ts2 += red2[row][i]; }
        float mu = ts / DIM;
        float var = ts2 / DIM - mu * mu;
        smu[row] = mu;
        srs[row] = rsqrtf(var + LN_EPS);
    }
    __syncthreads();
    {
        float gm0 = gamma[l], gm1 = gamma[l + 64];
        float bt0 = beta[l],  bt1 = beta[l + 64];
#pragma unroll
        for (int rr = 0; rr < 8; ++rr) {
            int row = w * 8 + rr;
            size_t gi = (size_t)(row0 + row) * DIM + l;
            out[gi]      = (sIn[row][l]      - smu[row]) * srs[row] * gm0 + bt0;
            out[gi + 64] = (sIn[row][l + 64] - smu[row]) * srs[row] * gm1 + bt1;
        }
    }
}

// ---------------------------------------------------------------------------
extern "C" void kernel_launch(void* const* d_in, const int* in_sizes, int n_in,
                              void* d_out, int out_size, void* d_ws, size_t ws_size,
                              hipStream_t stream) {
    const float* X     = (const float*)d_in[0];
    const float* rel   = (const float*)d_in[1];
    const int*   arows = (const int*)d_in[2];
    const int*   acols = (const int*)d_in[3];
    const float* avals = (const float*)d_in[4];
    const float* Wf    = (const float*)d_in[5];
    const float* bf    = (const float*)d_in[6];
    const float* Wr    = (const float*)d_in[7];
    const float* br    = (const float*)d_in[8];
    const float* rw    = (const float*)d_in[9];
    const float* Wg    = (const float*)d_in[10];
    const float* bg    = (const float*)d_in[11];
    const float* gamma = (const float*)d_in[12];
    const float* beta  = (const float*)d_in[13];
    float* out = (float*)d_out;

    // workspace layout (~156 MB):
    //   Yb      25.6 MB  bf16 Y = X@W1 in [4][N][32] (split) / Xb (fallback)
    //   edges   25.6 MB  bucketed (col,val) words
    //   counts   1.6 MB  CSR row starts (split) / hist counts (fallback)
    //   chunks/bfr/wsm/bcnt(padded)/bstart  small
    //   PH/PL    0.4 MB  packed hi/lo weight fragments
    //   msgs   102.4 MB  [R][N][D] bf16 relu'd messages; edges2 aliases it
    const size_t XB_B = (size_t)N_NODES * DIM * 2;
    const size_t ED_B = (size_t)NREL * NEDGE * 4;
    const size_t CT_B = (size_t)NREL * N_NODES * 4;
    char* p = (char*)d_ws;
    unsigned short* Yb     = (unsigned short*)p;  p += XB_B;
    unsigned int*   edges  = (unsigned int*)p;    p += ED_B;
    int*            counts = (int*)p;             p += CT_B;   // rowstart in split path
    int*            chunks = (int*)p;             p += 512 * 4;
    float*          bfr    = (float*)p;           p += NREL * DIM * 4;
    float*          wsm    = (float*)p;           p += 64 * 4;
    int*            bcnt   = (int*)p;             p += NREL * NBUCK * BCNT_STRIDE * 4;
    int*            bstart = (int*)p;             p += (NREL * NBUCK + 1) * 4;
    unsigned short* PH     = (unsigned short*)p;  p += 6 * 16384 * 2;
    unsigned short* PL     = (unsigned short*)p;  p += 6 * 16384 * 2;
    size_t off = (size_t)(p - (char*)d_ws);
    off = (off + 255) & ~(size_t)255;
    unsigned short* msgs = (unsigned short*)((char*)d_ws + off);
    unsigned long long* edges2 = (unsigned long long*)msgs;   // alias, pre-gather
    const size_t need = off + (size_t)NREL * N_NODES * DIM * 2;
    const bool split = (ws_size >= need);

    prep_kernel<<<1, 512, 0, stream>>>(rel, Wf, bf, rw, bfr, wsm);
    pack_kernel<<<dim3(64, 6), 256, 0, stream>>>(Wf, Wr, Wg, PH, PL);

    if (split) {
        y_kernel<<<N_NODES / 32, 256, 0, stream>>>(X, PH, PL, Yb);
        hipMemsetAsync(bcnt, 0,
                       (size_t)NREL * NBUCK * BCNT_STRIDE * sizeof(int), stream);
        const int AB = (NEDGE + P1_EDGES - 1) / P1_EDGES;   // 391
        binA_kernel<<<dim3(AB, NREL), 256, 0, stream>>>(
            arows, acols, avals, bcnt, edges2);
        bscan_kernel<<<1, 1024, 0, stream>>>(bcnt, bstart);
        binB_kernel<<<dim3(NBUCK, NREL), 256, 0, stream>>>(
            edges2, bcnt, bstart, counts, edges);
        gather_kernel<<<dim3((N_NODES + 63) / 64, NREL * 4), 256, 0, stream>>>(
            Yb, counts, edges, bfr, msgs);
        gemm2_kernel<<<N_NODES / 32, 256, 0, stream>>>(
            msgs, X, PH, PL, br, wsm, bg, gamma, beta, out);
    } else {
        xb_kernel<<<N_NODES * DIM / 4 / 256, 256, 0, stream>>>(X, Yb);
        const int EB = (NEDGE + 255) / 256;
        const int M = NREL * N_NODES;
        const int nch = (M + 1023) / 1024;
        hipMemsetAsync(counts, 0, (size_t)M * sizeof(int), stream);
        hist_kernel<<<dim3(EB, NREL), 256, 0, stream>>>(arows, counts);
        scan1_kernel<<<nch, 256, 0, stream>>>(counts, chunks, M);
        scan2_kernel<<<1, 512, 0, stream>>>(chunks, nch);
        reorder_kernel<<<dim3(EB, NREL), 256, 0, stream>>>(
            arows, acols, avals, counts, chunks, edges);
        mega_kernel<<<N_NODES / 32, 256, 0, stream>>>(
            Yb, X, counts, chunks, edges, Wf, bfr, Wr, br, wsm,
            Wg, bg, gamma, beta, out);
    }
}

// Round 9
// 590.162 us; speedup vs baseline: 1.1332x; 1.1332x over previous
//
#include <hip/hip_runtime.h>
#include <math.h>

#define N_NODES 100000
#define DIM 128
#define NREL 4
#define NEDGE 1600000
#define LN_EPS 1e-3f

#define NBUCK 196          // ceil(N_NODES/512) row-buckets of 512 rows
#define BCAP 10240         // capacity per (rel,bucket); mean 8192, sd ~90
#define P1_VPT 16
#define P1_EDGES 4096      // 256 * P1_VPT
#define BCNT_STRIDE 16     // one counter per 64B line (XCD atomic ping-pong fix)

typedef __attribute__((ext_vector_type(8))) short bf16x8;
typedef __attribute__((ext_vector_type(4))) float f32x4;

__device__ __forceinline__ float bf2f(unsigned short b) {
    return __uint_as_float(((unsigned int)b) << 16);
}
__device__ __forceinline__ unsigned short f2bf(float f) {
    unsigned int u = __float_as_uint(f);
    u += 0x7FFFu + ((u >> 16) & 1u);      // RN-even
    return (unsigned short)(u >> 16);
}

// ---------------------------------------------------------------------------
// Prep: bfr[r][d] = b_fuse[d] + sum_k rel[r][k]*W_fuse[D+k][d]; softmax(rel_w)
// ---------------------------------------------------------------------------
__global__ __launch_bounds__(512) void prep_kernel(
    const float* __restrict__ rel_emb, const float* __restrict__ W_fuse,
    const float* __restrict__ b_fuse, const float* __restrict__ rel_weights,
    float* __restrict__ bfr, float* __restrict__ wsm)
{
    int t = threadIdx.x;
    int r = t >> 7;
    int d = t & 127;
    float acc = b_fuse[d];
    for (int k = 0; k < DIM; ++k)
        acc += rel_emb[r * DIM + k] * W_fuse[(DIM + k) * DIM + d];
    bfr[r * DIM + d] = acc;
    if (t < NREL) {
        float m = rel_weights[0];
        for (int i = 1; i < NREL; ++i) m = fmaxf(m, rel_weights[i]);
        float s = 0.f;
        for (int i = 0; i < NREL; ++i) s += expf(rel_weights[i] - m);
        wsm[t] = expf(rel_weights[t] - m) / s;
    }
}

// ---------------------------------------------------------------------------
// Pack weights into MFMA B-fragment order, split hi/lo bf16.
// mat: 0=W_fuse[:128], 1..4=W_rel[r], 5=W_gate.
// ---------------------------------------------------------------------------
__global__ __launch_bounds__(256) void pack_kernel(
    const float* __restrict__ Wf, const float* __restrict__ Wr,
    const float* __restrict__ Wg,
    unsigned short* __restrict__ PH, unsigned short* __restrict__ PL)
{
    int mat = blockIdx.y;
    int idx = blockIdx.x * 256 + threadIdx.x;   // 0..16383
    int j = idx & 7;
    int lane = (idx >> 3) & 63;
    int ntile = (idx >> 9) & 7;
    int kblk = idx >> 12;
    int k = kblk * 32 + (lane >> 4) * 8 + j;
    int n = ntile * 16 + (lane & 15);
    const float* src = (mat == 0) ? Wf :
                       (mat == 5) ? Wg : (Wr + (size_t)(mat - 1) * DIM * DIM);
    float w = src[k * DIM + n];
    unsigned short hi = f2bf(w);
    float lo = w - bf2f(hi);
    PH[mat * 16384 + idx] = hi;
    PL[mat * 16384 + idx] = f2bf(lo);
}

// ---------------------------------------------------------------------------
// X (fp32) -> Xb (bf16)  [fallback path only]
// ---------------------------------------------------------------------------
__global__ __launch_bounds__(256) void xb_kernel(
    const float* __restrict__ X, unsigned short* __restrict__ Xb)
{
    int idx = blockIdx.x * 256 + threadIdx.x;   // N*DIM/4 exact
    float4 f = ((const float4*)X)[idx];
    ushort4 o;
    o.x = f2bf(f.x); o.y = f2bf(f.y); o.z = f2bf(f.z); o.w = f2bf(f.w);
    ((ushort4*)Xb)[idx] = o;
}

// ---------------------------------------------------------------------------
// Y = X @ W_fuse[:128]  (dense MFMA, hi/lo A and B, 3-pass) -> bf16 Yb.
// Yb layout is DIM-SPLIT: [2][N][64] — 128B half-rows. R8 proved the L2
// fill granule is 128B (64B quarter-rows caused 2x over-fetch: 621->910MB),
// so half-split is the finest granule-aligned working-set reduction.
// ---------------------------------------------------------------------------
__global__ __launch_bounds__(256) void y_kernel(
    const float* __restrict__ X,
    const unsigned short* __restrict__ PH,
    const unsigned short* __restrict__ PL,
    unsigned short* __restrict__ Yb)
{
    __shared__ unsigned short sXh[32 * 128];
    __shared__ unsigned short sXl[32 * 128];

    int t = threadIdx.x;
    int row0 = blockIdx.x * 32;
    int wv = t >> 6, l = t & 63, lq = l >> 4, lm = l & 15;

    const float4* Xs = (const float4*)(X + (size_t)row0 * DIM);
#pragma unroll
    for (int it = 0; it < 2; ++it) {
        int i = t + it * 256;
        float4 f0 = Xs[2 * i];
        float4 f1 = Xs[2 * i + 1];
        float e[8] = {f0.x, f0.y, f0.z, f0.w, f1.x, f1.y, f1.z, f1.w};
        unsigned short h[8], lo[8];
#pragma unroll
        for (int j = 0; j < 8; ++j) {
            h[j] = f2bf(e[j]);
            lo[j] = f2bf(e[j] - bf2f(h[j]));
        }
        uint4 hv, lv;
        hv.x = ((unsigned int)h[1] << 16) | h[0];
        hv.y = ((unsigned int)h[3] << 16) | h[2];
        hv.z = ((unsigned int)h[5] << 16) | h[4];
        hv.w = ((unsigned int)h[7] << 16) | h[6];
        lv.x = ((unsigned int)lo[1] << 16) | lo[0];
        lv.y = ((unsigned int)lo[3] << 16) | lo[2];
        lv.z = ((unsigned int)lo[5] << 16) | lo[4];
        lv.w = ((unsigned int)lo[7] << 16) | lo[6];
        int row = i >> 4, ck = i & 15;
        int off = row * 256 + ((ck * 16) ^ ((row & 7) << 4));
        *(uint4*)((char*)sXh + off) = hv;
        *(uint4*)((char*)sXl + off) = lv;
    }
    __syncthreads();

    f32x4 acc[2][2];
#pragma unroll
    for (int mt = 0; mt < 2; ++mt)
#pragma unroll
        for (int ni = 0; ni < 2; ++ni)
#pragma unroll
            for (int r = 0; r < 4; ++r) acc[mt][ni][r] = 0.f;

#pragma unroll
    for (int kb = 0; kb < 4; ++kb) {
        int c0 = kb * 64 + lq * 16;
        int r0 = lm, r1 = 16 + lm;
        int o0 = r0 * 256 + (c0 ^ ((r0 & 7) << 4));
        int o1 = r1 * 256 + (c0 ^ ((r1 & 7) << 4));
        bf16x8 ah0 = *(const bf16x8*)((char*)sXh + o0);
        bf16x8 ah1 = *(const bf16x8*)((char*)sXh + o1);
        bf16x8 al0 = *(const bf16x8*)((char*)sXl + o0);
        bf16x8 al1 = *(const bf16x8*)((char*)sXl + o1);
#pragma unroll
        for (int ni = 0; ni < 2; ++ni) {
            int nt_ = wv * 2 + ni;
            int fi = ((kb * 8 + nt_) * 64 + l) << 3;
            bf16x8 bh = *(const bf16x8*)(PH + fi);
            bf16x8 bl = *(const bf16x8*)(PL + fi);
            acc[0][ni] = __builtin_amdgcn_mfma_f32_16x16x32_bf16(ah0, bh, acc[0][ni], 0, 0, 0);
            acc[1][ni] = __builtin_amdgcn_mfma_f32_16x16x32_bf16(ah1, bh, acc[1][ni], 0, 0, 0);
            acc[0][ni] = __builtin_amdgcn_mfma_f32_16x16x32_bf16(ah0, bl, acc[0][ni], 0, 0, 0);
            acc[1][ni] = __builtin_amdgcn_mfma_f32_16x16x32_bf16(ah1, bl, acc[1][ni], 0, 0, 0);
            acc[0][ni] = __builtin_amdgcn_mfma_f32_16x16x32_bf16(al0, bh, acc[0][ni], 0, 0, 0);
            acc[1][ni] = __builtin_amdgcn_mfma_f32_16x16x32_bf16(al1, bh, acc[1][ni], 0, 0, 0);
        }
    }
    __syncthreads();
#pragma unroll
    for (int mt = 0; mt < 2; ++mt)
#pragma unroll
    for (int ni = 0; ni < 2; ++ni) {
        int colg = (wv * 2 + ni) * 16 + lm;
#pragma unroll
        for (int r = 0; r < 4; ++r) {
            int row = mt * 16 + lq * 4 + r;
            sXh[row * 128 + colg] = f2bf(acc[mt][ni][r]);
        }
    }
    __syncthreads();
    // write out in [half][node][64] layout
    const uint4* s4 = (const uint4*)sXh;
#pragma unroll
    for (int it = 0; it < 2; ++it) {
        int i = t + it * 256;
        int row = i >> 4, ck = i & 15;
        int half = ck >> 3, c64 = ck & 7;      // 8-dim granule within half
        uint4* dst = (uint4*)(Yb + (size_t)half * N_NODES * 64 +
                              (size_t)(row0 + row) * 64);
        dst[c64] = s4[i];
    }
}

// ---------------------------------------------------------------------------
// binA: LDS-staged multisplit of edges into 196 row-buckets per relation.
// bcnt is line-padded (BCNT_STRIDE): 1 counter per 64B line to kill
// cross-XCD same-line atomic ping-pong.
// ---------------------------------------------------------------------------
__global__ __launch_bounds__(256) void binA_kernel(
    const int* __restrict__ arows, const int* __restrict__ acols,
    const float* __restrict__ avals,
    int* __restrict__ bcnt,                 // [NREL*NBUCK*BCNT_STRIDE], zeroed
    unsigned long long* __restrict__ edges2)
{
    __shared__ int hist[256];
    __shared__ int hoff[256];
    __shared__ int gbase[NBUCK];
    __shared__ unsigned long long stage[P1_EDGES];
    __shared__ unsigned short sbid[P1_EDGES];

    int t = threadIdx.x;
    int rl = blockIdx.y;
    int e0 = blockIdx.x * P1_EDGES;

    hist[t] = 0;
    __syncthreads();

    int b[P1_VPT], rank[P1_VPT], rloc[P1_VPT];
    unsigned int pay[P1_VPT];
#pragma unroll
    for (int i = 0; i < P1_VPT; ++i) {
        int e = e0 + i * 256 + t;
        b[i] = -1;
        if (e < NEDGE) {
            size_t off = (size_t)rl * NEDGE + e;
            int row = arows[off];
            unsigned int vb = __float_as_uint(avals[off]);
            vb += 0x7FFFu + ((vb >> 16) & 1u);      // RN-even to bf16
            pay[i] = ((unsigned int)acols[off] << 15) | ((vb >> 16) & 0x7FFFu);
            b[i] = row >> 9;
            rloc[i] = row & 511;
            rank[i] = atomicAdd(&hist[b[i]], 1);
        }
    }
    __syncthreads();

    // exclusive scan of hist -> hoff
    int v = hist[t];
    int run = v;
    hoff[t] = run;
    __syncthreads();
    for (int o = 1; o < 256; o <<= 1) {
        int other = (t >= o) ? hoff[t - o] : 0;
        __syncthreads();
        run += other;
        hoff[t] = run;
        __syncthreads();
    }
    hoff[t] = run - v;      // exclusive
    if (t < NBUCK) {
        int g = (v > 0) ? atomicAdd(&bcnt[(rl * NBUCK + t) * BCNT_STRIDE], v) : 0;
        gbase[t] = (rl * NBUCK + t) * BCAP + g;
    }
    __syncthreads();

#pragma unroll
    for (int i = 0; i < P1_VPT; ++i) {
        if (b[i] >= 0) {
            int slot = hoff[b[i]] + rank[i];
            stage[slot] = ((unsigned long long)rloc[i] << 32) | pay[i];
            sbid[slot] = (unsigned short)b[i];
        }
    }
    __syncthreads();

    int total = hoff[NBUCK - 1] + hist[NBUCK - 1];
    for (int idx = t; idx < total; idx += 256) {
        int bb = sbid[idx];
        int gaddr = gbase[bb] + (idx - hoff[bb]);
        if (gaddr - (rl * NBUCK + bb) * BCAP < BCAP)
            edges2[gaddr] = stage[idx];
    }
}

// ---------------------------------------------------------------------------
// bscan: exclusive scan of the 784 bucket counts -> bstart[784]
// ---------------------------------------------------------------------------
__global__ __launch_bounds__(1024) void bscan_kernel(
    const int* __restrict__ bcnt, int* __restrict__ bstart)
{
    __shared__ int s[1024];
    int t = threadIdx.x;
    int v = (t < NREL * NBUCK) ? min(bcnt[t * BCNT_STRIDE], BCAP) : 0;
    int run = v;
    s[t] = run;
    __syncthreads();
    for (int o = 1; o < 1024; o <<= 1) {
        int other = (t >= o) ? s[t - o] : 0;
        __syncthreads();
        run += other;
        s[t] = run;
        __syncthreads();
    }
    if (t < NREL * NBUCK) bstart[t] = run - v;
}

// ---------------------------------------------------------------------------
// binB: per (bucket, relation): LDS-hist 512 rows -> CSR starts + scatter.
// ---------------------------------------------------------------------------
__global__ __launch_bounds__(256) void binB_kernel(
    const unsigned long long* __restrict__ edges2,
    const int* __restrict__ bcnt, const int* __restrict__ bstart,
    int* __restrict__ rowstart, unsigned int* __restrict__ edges)
{
    __shared__ int rcnt[512];
    __shared__ int rpos[512];
    __shared__ int sc[256];

    int t = threadIdx.x;
    int b = blockIdx.x, rl = blockIdx.y;
    int gb = rl * NBUCK + b;
    int cnt = min(bcnt[gb * BCNT_STRIDE], BCAP);
    const unsigned long long* src = edges2 + (size_t)gb * BCAP;
    int row0 = b << 9;
    int nrows = min(512, N_NODES - row0);

    rcnt[t] = 0; rcnt[t + 256] = 0;
    __syncthreads();
    for (int e = t; e < cnt; e += 256)
        atomicAdd(&rcnt[(int)(src[e] >> 32)], 1);
    __syncthreads();

    int v0 = rcnt[2 * t], v1 = rcnt[2 * t + 1];
    int tsum = v0 + v1;
    int run = tsum;
    sc[t] = run;
    __syncthreads();
    for (int o = 1; o < 256; o <<= 1) {
        int other = (t >= o) ? sc[t - o] : 0;
        __syncthreads();
        run += other;
        sc[t] = run;
        __syncthreads();
    }
    int base = bstart[gb];
    int excl = base + run - tsum;
    rpos[2 * t] = excl;
    rpos[2 * t + 1] = excl + v0;
    __syncthreads();

    for (int i = t; i < nrows; i += 256)
        rowstart[rl * N_NODES + row0 + i] = rpos[i];
    __syncthreads();

    for (int e = t; e < cnt; e += 256) {
        unsigned long long s = src[e];
        int p = atomicAdd(&rpos[(int)(s >> 32)], 1);
        edges[p] = (unsigned int)s;
    }
}

// ---------------------------------------------------------------------------
// Gather over dim-split Yb[2][N][64]: grid.y = (half<<2)|rel. 8-lane groups,
// each lane owns 8 dims of the 64-dim half (16B uint4 per edge). 4-deep
// pipeline. Half-split = best measured config (R7: 185us, FETCH 621MB);
// quarter-split regressed (R8: 128B fill granule, 2x over-fetch).
// ---------------------------------------------------------------------------
#define FMA8(acc, v, q)                                    \
    acc[0] += v * __uint_as_float((q).x << 16);            \
    acc[1] += v * __uint_as_float((q).x & 0xFFFF0000u);    \
    acc[2] += v * __uint_as_float((q).y << 16);            \
    acc[3] += v * __uint_as_float((q).y & 0xFFFF0000u);    \
    acc[4] += v * __uint_as_float((q).z << 16);            \
    acc[5] += v * __uint_as_float((q).z & 0xFFFF0000u);    \
    acc[6] += v * __uint_as_float((q).w << 16);            \
    acc[7] += v * __uint_as_float((q).w & 0xFFFF0000u);

__global__ __launch_bounds__(256) void gather_kernel(
    const unsigned short* __restrict__ Yb,   // [2][N][64]
    const int* __restrict__ rowstart,        // CSR starts, [NREL*N_NODES]
    const unsigned int* __restrict__ edges,
    const float* __restrict__ bfr,
    unsigned short* __restrict__ msgs)       // [R][N][128] bf16 (relu'd)
{
    int t = threadIdx.x;
    int grp = t >> 3, lane = t & 7;          // 32 groups x 8 lanes
    int row = blockIdx.x * 32 + grp;
    int rl = blockIdx.y & 3;
    int h  = blockIdx.y >> 2;
    int g = rl * N_NODES + row;
    int s = rowstart[g];
    int e = (g == NREL * N_NODES - 1) ? (NREL * NEDGE) : rowstart[g + 1];

    float a0[8], a1[8], a2[8], a3[8];
#pragma unroll
    for (int i = 0; i < 8; ++i) { a0[i] = 0.f; a1[i] = 0.f; a2[i] = 0.f; a3[i] = 0.f; }

    const uint4* Yb4 = (const uint4*)(Yb + (size_t)h * N_NODES * 64);
    int ee = s;
    int nrem = e - s;
    if (nrem >= 4) {
        unsigned int p0 = edges[ee], p1 = edges[ee + 1],
                     p2 = edges[ee + 2], p3 = edges[ee + 3];
        while (nrem >= 4) {
            uint4 q0 = Yb4[((size_t)(p0 >> 15) << 3) + lane];
            uint4 q1 = Yb4[((size_t)(p1 >> 15) << 3) + lane];
            uint4 q2 = Yb4[((size_t)(p2 >> 15) << 3) + lane];
            uint4 q3 = Yb4[((size_t)(p3 >> 15) << 3) + lane];
            float v0 = __uint_as_float((p0 & 0x7FFFu) << 16);
            float v1 = __uint_as_float((p1 & 0x7FFFu) << 16);
            float v2 = __uint_as_float((p2 & 0x7FFFu) << 16);
            float v3 = __uint_as_float((p3 & 0x7FFFu) << 16);
            nrem -= 4; ee += 4;
            if (nrem >= 4) {       // prefetch next edge words under the FMAs
                p0 = edges[ee + 0]; p1 = edges[ee + 1];
                p2 = edges[ee + 2]; p3 = edges[ee + 3];
            }
            FMA8(a0, v0, q0)
            FMA8(a1, v1, q1)
            FMA8(a2, v2, q2)
            FMA8(a3, v3, q3)
        }
    }
    while (nrem > 0) {
        unsigned int p = edges[ee];
        uint4 q = Yb4[((size_t)(p >> 15) << 3) + lane];
        float v = __uint_as_float((p & 0x7FFFu) << 16);
        FMA8(a0, v, q)
        ++ee; --nrem;
    }
#pragma unroll
    for (int i = 0; i < 8; ++i) a0[i] += a1[i] + a2[i] + a3[i];

    // fused epilogue: + bfr, relu, bf16  (this pass owns dims h*64+lane*8..+8)
    const float4* bb = (const float4*)(bfr + rl * DIM + h * 64 + lane * 8);
    float4 b0 = bb[0], b1 = bb[1];
    float f0 = fmaxf(a0[0] + b0.x, 0.f), f1 = fmaxf(a0[1] + b0.y, 0.f);
    float f2 = fmaxf(a0[2] + b0.z, 0.f), f3 = fmaxf(a0[3] + b0.w, 0.f);
    float f4 = fmaxf(a0[4] + b1.x, 0.f), f5 = fmaxf(a0[5] + b1.y, 0.f);
    float f6 = fmaxf(a0[6] + b1.z, 0.f), f7 = fmaxf(a0[7] + b1.w, 0.f);
    uint4 o;
    o.x = ((unsigned int)f2bf(f1) << 16) | f2bf(f0);
    o.y = ((unsigned int)f2bf(f3) << 16) | f2bf(f2);
    o.z = ((unsigned int)f2bf(f5) << 16) | f2bf(f4);
    o.w = ((unsigned int)f2bf(f7) << 16) | f2bf(f6);
    ((uint4*)(msgs + ((size_t)g << 7) + h * 64))[lane] = o;
}

// ---------------------------------------------------------------------------
// gemm2: per 32-row tile: for rl: stage relu'd msgs -> GEMM2 (2-pass, B hi/lo),
// comb in regs; then gate GEMM from X (fp32->bf16 in-kernel), residual + LN.
// ---------------------------------------------------------------------------
__global__ __launch_bounds__(256) void gemm2_kernel(
    const unsigned short* __restrict__ msgs,
    const float* __restrict__ X,
    const unsigned short* __restrict__ PH,
    const unsigned short* __restrict__ PL,
    const float* __restrict__ br,
    const float* __restrict__ wsm,
    const float* __restrict__ bg,
    const float* __restrict__ gamma,
    const float* __restrict__ beta,
    float* __restrict__ out)
{
    __shared__ float sX[32 * 132];          // LN buffer; first 8KB doubles as sB
    __shared__ float red[32][8], red2[32][8];
    __shared__ float smu[32], srs[32];
    unsigned short* sB = (unsigned short*)sX;

    int t = threadIdx.x;
    int row0 = blockIdx.x * 32;
    int wv = t >> 6, l = t & 63, lq = l >> 4, lm = l & 15;

    f32x4 comb[2][2];
#pragma unroll
    for (int mt = 0; mt < 2; ++mt)
#pragma unroll
        for (int ni = 0; ni < 2; ++ni)
#pragma unroll
            for (int r = 0; r < 4; ++r) comb[mt][ni][r] = 0.f;

    // prologue: stage regs for rl=0
    uint4 m0, m1;
    {
        const uint4* src = (const uint4*)msgs + ((size_t)row0 << 4);
        m0 = src[t]; m1 = src[t + 256];
    }
    float4 xa, xb_, xc, xd;   // X gate tile staged regs (loaded during rl=3)

    for (int rl = 0; rl < NREL; ++rl) {
        __syncthreads();       // sB free (prev GEMM2 A-reads done)
        {
            int i0 = t, i1 = t + 256;
            int row = i0 >> 4, ck = i0 & 15;
            *(uint4*)((char*)sB + row * 256 + ((ck * 16) ^ ((row & 7) << 4))) = m0;
            row = i1 >> 4; ck = i1 & 15;
            *(uint4*)((char*)sB + row * 256 + ((ck * 16) ^ ((row & 7) << 4))) = m1;
        }
        if (rl < NREL - 1) {   // T14: issue next-tile loads, land after GEMM2
            const uint4* src = (const uint4*)msgs +
                ((size_t)((rl + 1) * N_NODES + row0) << 4);
            m0 = src[t]; m1 = src[t + 256];
        } else {
            const float4* Xs = (const float4*)(X + (size_t)row0 * DIM);
            xa = Xs[2 * t];       xb_ = Xs[2 * t + 1];
            xc = Xs[2 * (t + 256)]; xd = Xs[2 * (t + 256) + 1];
        }
        __syncthreads();       // sB ready

        const unsigned short* ph2 = PH + (size_t)(1 + rl) * 16384;
        const unsigned short* pl2 = PL + (size_t)(1 + rl) * 16384;
        f32x4 acc[2][2];
#pragma unroll
        for (int mt = 0; mt < 2; ++mt)
#pragma unroll
            for (int ni = 0; ni < 2; ++ni)
#pragma unroll
                for (int r = 0; r < 4; ++r) acc[mt][ni][r] = 0.f;

#pragma unroll
        for (int kb = 0; kb < 4; ++kb) {
            int c0 = kb * 64 + lq * 16;
            int r0 = lm, r1 = 16 + lm;
            int o0 = r0 * 256 + (c0 ^ ((r0 & 7) << 4));
            int o1 = r1 * 256 + (c0 ^ ((r1 & 7) << 4));
            bf16x8 a0v = *(const bf16x8*)((char*)sB + o0);
            bf16x8 a1v = *(const bf16x8*)((char*)sB + o1);
#pragma unroll
            for (int ni = 0; ni < 2; ++ni) {
                int nt_ = wv * 2 + ni;
                int fi = ((kb * 8 + nt_) * 64 + l) << 3;
                bf16x8 bh = *(const bf16x8*)(ph2 + fi);
                bf16x8 bl = *(const bf16x8*)(pl2 + fi);
                acc[0][ni] = __builtin_amdgcn_mfma_f32_16x16x32_bf16(a0v, bh, acc[0][ni], 0, 0, 0);
                acc[1][ni] = __builtin_amdgcn_mfma_f32_16x16x32_bf16(a1v, bh, acc[1][ni], 0, 0, 0);
                acc[0][ni] = __builtin_amdgcn_mfma_f32_16x16x32_bf16(a0v, bl, acc[0][ni], 0, 0, 0);
                acc[1][ni] = __builtin_amdgcn_mfma_f32_16x16x32_bf16(a1v, bl, acc[1][ni], 0, 0, 0);
            }
        }
        {
            float wr_ = wsm[rl];
#pragma unroll
            for (int mt = 0; mt < 2; ++mt)
#pragma unroll
            for (int ni = 0; ni < 2; ++ni) {
                int colg = (wv * 2 + ni) * 16 + lm;
                float b = br[rl * DIM + colg];
#pragma unroll
                for (int r = 0; r < 4; ++r)
                    comb[mt][ni][r] += wr_ * (acc[mt][ni][r] + b);
            }
        }
    }

    // ---- gate: stage X (hi-bf16) into sB
    __syncthreads();
    {
        float e0[8] = {xa.x, xa.y, xa.z, xa.w, xb_.x, xb_.y, xb_.z, xb_.w};
        uint4 hv;
        hv.x = ((unsigned int)f2bf(e0[1]) << 16) | f2bf(e0[0]);
        hv.y = ((unsigned int)f2bf(e0[3]) << 16) | f2bf(e0[2]);
        hv.z = ((unsigned int)f2bf(e0[5]) << 16) | f2bf(e0[4]);
        hv.w = ((unsigned int)f2bf(e0[7]) << 16) | f2bf(e0[6]);
        int i = t, row = i >> 4, ck = i & 15;
        *(uint4*)((char*)sB + row * 256 + ((ck * 16) ^ ((row & 7) << 4))) = hv;
        float e1[8] = {xc.x, xc.y, xc.z, xc.w, xd.x, xd.y, xd.z, xd.w};
        hv.x = ((unsigned int)f2bf(e1[1]) << 16) | f2bf(e1[0]);
        hv.y = ((unsigned int)f2bf(e1[3]) << 16) | f2bf(e1[2]);
        hv.z = ((unsigned int)f2bf(e1[5]) << 16) | f2bf(e1[4]);
        hv.w = ((unsigned int)f2bf(e1[7]) << 16) | f2bf(e1[6]);
        i = t + 256; row = i >> 4; ck = i & 15;
        *(uint4*)((char*)sB + row * 256 + ((ck * 16) ^ ((row & 7) << 4))) = hv;
    }
    __syncthreads();

    f32x4 accg[2][2];
#pragma unroll
    for (int mt = 0; mt < 2; ++mt)
#pragma unroll
        for (int ni = 0; ni < 2; ++ni)
#pragma unroll
            for (int r = 0; r < 4; ++r) accg[mt][ni][r] = 0.f;

    const unsigned short* phg = PH + (size_t)5 * 16384;
    const unsigned short* plg = PL + (size_t)5 * 16384;
#pragma unroll
    for (int kb = 0; kb < 4; ++kb) {
        int c0 = kb * 64 + lq * 16;
        int r0 = lm, r1 = 16 + lm;
        bf16x8 a0v = *(const bf16x8*)((char*)sB + r0 * 256 + (c0 ^ ((r0 & 7) << 4)));
        bf16x8 a1v = *(const bf16x8*)((char*)sB + r1 * 256 + (c0 ^ ((r1 & 7) << 4)));
#pragma unroll
        for (int ni = 0; ni < 2; ++ni) {
            int nt_ = wv * 2 + ni;
            int fi = ((kb * 8 + nt_) * 64 + l) << 3;
            bf16x8 bh = *(const bf16x8*)(phg + fi);
            bf16x8 bl = *(const bf16x8*)(plg + fi);
            accg[0][ni] = __builtin_amdgcn_mfma_f32_16x16x32_bf16(a0v, bh, accg[0][ni], 0, 0, 0);
            accg[1][ni] = __builtin_amdgcn_mfma_f32_16x16x32_bf16(a1v, bh, accg[1][ni], 0, 0, 0);
            accg[0][ni] = __builtin_amdgcn_mfma_f32_16x16x32_bf16(a0v, bl, accg[0][ni], 0, 0, 0);
            accg[1][ni] = __builtin_amdgcn_mfma_f32_16x16x32_bf16(a1v, bl, accg[1][ni], 0, 0, 0);
        }
    }
    __syncthreads();   // all sB ds_reads done; sX may overwrite

    // ---- stage the fp32 X tile (already in regs) into sX linear
    {
        int i = t, row = i >> 4, c = (i & 15) << 3;
        *(float4*)&sX[row * 132 + c] = xa;
        *(float4*)&sX[row * 132 + c + 4] = xb_;
        i = t + 256; row = i >> 4; c = (i & 15) << 3;
        *(float4*)&sX[row * 132 + c] = xc;
        *(float4*)&sX[row * 132 + c + 4] = xd;
    }
    __syncthreads();

    // ---- x = X + sigmoid(gate)*comb, in place in sX
#pragma unroll
    for (int mt = 0; mt < 2; ++mt)
#pragma unroll
    for (int ni = 0; ni < 2; ++ni) {
        int colg = (wv * 2 + ni) * 16 + lm;
        float bgv = bg[colg];
#pragma unroll
        for (int r = 0; r < 4; ++r) {
            int row = mt * 16 + lq * 4 + r;
            float g = 1.f / (1.f + expf(-(accg[mt][ni][r] + bgv)));
            sX[row * 132 + colg] += g * comb[mt][ni][r];
        }
    }
    __syncthreads();

    // ---- LayerNorm
    {
        int row = t >> 3, seg = t & 7;
        float s = 0.f, s2 = 0.f;
#pragma unroll
        for (int i = 0; i < 16; ++i) {
            float v = sX[row * 132 + seg * 16 + i];
            s += v; s2 += v * v;
        }
        red[row][seg] = s;
        red2[row][seg] = s2;
    }
    __syncthreads();
    if ((t & 7) == 0) {
        int row = t >> 3;
        float ts = 0.f, ts2 = 0.f;
#pragma unroll
        for (int i = 0; i < 8; ++i) { ts += red[row][i]; ts2 += red2[row][i]; }
        float mu = ts / DIM;
        float var = ts2 / DIM - mu * mu;
        smu[row] = mu;
        srs[row] = rsqrtf(var + LN_EPS);
    }
    __syncthreads();
    {
        float gm0 = gamma[l], gm1 = gamma[l + 64];
        float bt0 = beta[l],  bt1 = beta[l + 64];
#pragma unroll
        for (int rr = 0; rr < 8; ++rr) {
            int row = wv * 8 + rr;
            size_t gi = (size_t)(row0 + row) * DIM + l;
            out[gi]      = (sX[row * 132 + l]      - smu[row]) * srs[row] * gm0 + bt0;
            out[gi + 64] = (sX[row * 132 + l + 64] - smu[row]) * srs[row] * gm1 + bt1;
        }
    }
}

// ---------------------------------------------------------------------------
// FALLBACK path kernels (only if ws too small): old CSR build + fused mega
// ---------------------------------------------------------------------------
__global__ __launch_bounds__(256) void hist_kernel(
    const int* __restrict__ arows, int* __restrict__ counts)
{
    int e = blockIdx.x * 256 + threadIdx.x;
    int rl = blockIdx.y;
    if (e < NEDGE) {
        int row = arows[(size_t)rl * NEDGE + e];
        atomicAdd(&counts[rl * N_NODES + row], 1);
    }
}

__global__ __launch_bounds__(256) void scan1_kernel(
    int* __restrict__ counts, int* __restrict__ chunksums, int M)
{
    __shared__ int s[256];
    int chunk = blockIdx.x, t = threadIdx.x;
    int base = chunk * 1024 + t * 4;
    int v0 = (base + 0 < M) ? counts[base + 0] : 0;
    int v1 = (base + 1 < M) ? counts[base + 1] : 0;
    int v2 = (base + 2 < M) ? counts[base + 2] : 0;
    int v3 = (base + 3 < M) ? counts[base + 3] : 0;
    int p1 = v0, p2 = v0 + v1, p3 = v0 + v1 + v2, tsum = p3 + v3;
    int run = tsum;
    s[t] = run;
    __syncthreads();
    for (int off = 1; off < 256; off <<= 1) {
        int other = (t >= off) ? s[t - off] : 0;
        __syncthreads();
        run += other;
        s[t] = run;
        __syncthreads();
    }
    int excl = run - tsum;
    if (t == 255) chunksums[chunk] = run;
    if (base + 0 < M) counts[base + 0] = excl;
    if (base + 1 < M) counts[base + 1] = excl + p1;
    if (base + 2 < M) counts[base + 2] = excl + p2;
    if (base + 3 < M) counts[base + 3] = excl + p3;
}

__global__ __launch_bounds__(512) void scan2_kernel(
    int* __restrict__ chunksums, int nchunks)
{
    __shared__ int s[512];
    int t = threadIdx.x;
    int v = (t < nchunks) ? chunksums[t] : 0;
    int run = v;
    s[t] = run;
    __syncthreads();
    for (int off = 1; off < 512; off <<= 1) {
        int other = (t >= off) ? s[t - off] : 0;
        __syncthreads();
        run += other;
        s[t] = run;
        __syncthreads();
    }
    if (t < nchunks) chunksums[t] = run - v;
}

__global__ __launch_bounds__(256) void reorder_kernel(
    const int* __restrict__ arows, const int* __restrict__ acols,
    const float* __restrict__ avals,
    int* __restrict__ counts, const int* __restrict__ chunks,
    unsigned int* __restrict__ edges)
{
    int e = blockIdx.x * 256 + threadIdx.x;
    int rl = blockIdx.y;
    if (e < NEDGE) {
        size_t off = (size_t)rl * NEDGE + e;
        int row = arows[off];
        int g = rl * N_NODES + row;
        int pos = atomicAdd(&counts[g], 1) + chunks[g >> 10];
        unsigned int vb = __float_as_uint(avals[off]);
        vb += 0x7FFFu + ((vb >> 16) & 1u);
        edges[pos] = ((unsigned int)acols[off] << 15) | ((vb >> 16) & 0x7FFFu);
    }
}

__global__ __launch_bounds__(256) void mega_kernel(
    const unsigned short* __restrict__ Xb,
    const float* __restrict__ X,
    const int* __restrict__ counts,
    const int* __restrict__ chunks,
    const unsigned int* __restrict__ edges,
    const float* __restrict__ W1,
    const float* __restrict__ bfr,
    const float* __restrict__ Wr,
    const float* __restrict__ br,
    const float* __restrict__ wsm,
    const float* __restrict__ Wg,
    const float* __restrict__ bg,
    const float* __restrict__ gamma,
    const float* __restrict__ beta,
    float* __restrict__ out)
{
    __shared__ float sIn[32][DIM];
    __shared__ float red[32][8], red2[32][8];
    __shared__ float smu[32], srs[32];

    int t = threadIdx.x;
    int row0 = blockIdx.x * 32;
    int w = t >> 6;
    int l = t & 63;
    int grp = t >> 5, lane = t & 31;

    float comb_acc[8][2];
#pragma unroll
    for (int rr = 0; rr < 8; ++rr) { comb_acc[rr][0] = 0.f; comb_acc[rr][1] = 0.f; }

    for (int rl = 0; rl < NREL; ++rl) {
        __syncthreads();
#pragma unroll
        for (int i = 0; i < 4; ++i) {
            int ln = grp * 4 + i;
            int g = rl * N_NODES + row0 + ln;
            int s = (g == 0) ? 0 : counts[g - 1] + chunks[(g - 1) >> 10];
            int e = counts[g] + chunks[g >> 10];
            float4 a0 = make_float4(0.f, 0.f, 0.f, 0.f);
            int ee = s;
            for (; ee < e; ++ee) {
                unsigned int p0 = edges[ee];
                const ushort4* x0 = (const ushort4*)(Xb + ((size_t)(p0 >> 15) << 7));
                ushort4 q0 = x0[lane];
                float v0 = __uint_as_float((p0 & 0x7FFFu) << 16);
                a0.x += v0 * bf2f(q0.x); a0.y += v0 * bf2f(q0.y);
                a0.z += v0 * bf2f(q0.z); a0.w += v0 * bf2f(q0.w);
            }
            ((float4*)&sIn[ln][0])[lane] = a0;
        }
        __syncthreads();

        float acc1[8][2];
#pragma unroll
        for (int rr = 0; rr < 8; ++rr) { acc1[rr][0] = 0.f; acc1[rr][1] = 0.f; }
        for (int k4 = 0; k4 < DIM / 4; ++k4) {
            float wa[4], wb4[4];
#pragma unroll
            for (int j = 0; j < 4; ++j) {
                wa[j]  = W1[(k4 * 4 + j) * DIM + l];
                wb4[j] = W1[(k4 * 4 + j) * DIM + l + 64];
            }
#pragma unroll
            for (int rr = 0; rr < 8; ++rr) {
                float4 m = *(const float4*)&sIn[w * 8 + rr][k4 * 4];
                acc1[rr][0] += m.x * wa[0]  + m.y * wa[1]  + m.z * wa[2]  + m.w * wa[3];
                acc1[rr][1] += m.x * wb4[0] + m.y * wb4[1] + m.z * wb4[2] + m.w * wb4[3];
            }
        }
        __syncthreads();
        {
            float b0 = bfr[rl * DIM + l], b1 = bfr[rl * DIM + l + 64];
#pragma unroll
            for (int rr = 0; rr < 8; ++rr) {
                sIn[w * 8 + rr][l]      = fmaxf(acc1[rr][0] + b0, 0.f);
                sIn[w * 8 + rr][l + 64] = fmaxf(acc1[rr][1] + b1, 0.f);
            }
        }
        __syncthreads();

        const float* W2 = Wr + (size_t)rl * DIM * DIM;
        float acc2[8][2];
#pragma unroll
        for (int rr = 0; rr < 8; ++rr) { acc2[rr][0] = 0.f; acc2[rr][1] = 0.f; }
        for (int k4 = 0; k4 < DIM / 4; ++k4) {
            float wa[4], wb4[4];
#pragma unroll
            for (int j = 0; j < 4; ++j) {
                wa[j]  = W2[(k4 * 4 + j) * DIM + l];
                wb4[j] = W2[(k4 * 4 + j) * DIM + l + 64];
            }
#pragma unroll
            for (int rr = 0; rr < 8; ++rr) {
                float4 m = *(const float4*)&sIn[w * 8 + rr][k4 * 4];
                acc2[rr][0] += m.x * wa[0]  + m.y * wa[1]  + m.z * wa[2]  + m.w * wa[3];
                acc2[rr][1] += m.x * wb4[0] + m.y * wb4[1] + m.z * wb4[2] + m.w * wb4[3];
            }
        }
        {
            float wr_ = wsm[rl];
            float bb0 = br[rl * DIM + l], bb1 = br[rl * DIM + l + 64];
#pragma unroll
            for (int rr = 0; rr < 8; ++rr) {
                comb_acc[rr][0] += wr_ * (acc2[rr][0] + bb0);
                comb_acc[rr][1] += wr_ * (acc2[rr][1] + bb1);
            }
        }
    }

    __syncthreads();
    {
        const float4* src = (const float4*)(X + (size_t)row0 * DIM);
        float4* dst = (float4*)&sIn[0][0];
        for (int i = t; i < 32 * DIM / 4; i += 256) dst[i] = src[i];
    }
    __syncthreads();

    float accg[8][2];
#pragma unroll
    for (int rr = 0; rr < 8; ++rr) { accg[rr][0] = 0.f; accg[rr][1] = 0.f; }
    for (int k4 = 0; k4 < DIM / 4; ++k4) {
        float wa[4], wb4[4];
#pragma unroll
        for (int j = 0; j < 4; ++j) {
            wa[j]  = Wg[(k4 * 4 + j) * DIM + l];
            wb4[j] = Wg[(k4 * 4 + j) * DIM + l + 64];
        }
#pragma unroll
        for (int rr = 0; rr < 8; ++rr) {
            float4 m = *(const float4*)&sIn[w * 8 + rr][k4 * 4];
            accg[rr][0] += m.x * wa[0]  + m.y * wa[1]  + m.z * wa[2]  + m.w * wa[3];
            accg[rr][1] += m.x * wb4[0] + m.y * wb4[1] + m.z * wb4[2] + m.w * wb4[3];
        }
    }
    float xv[8][2];
    {
        float bg0 = bg[l], bg1 = bg[l + 64];
#pragma unroll
        for (int rr = 0; rr < 8; ++rr) {
            int row = w * 8 + rr;
            float g0 = 1.f / (1.f + expf(-(accg[rr][0] + bg0)));
            float g1 = 1.f / (1.f + expf(-(accg[rr][1] + bg1)));
            xv[rr][0] = sIn[row][l]      + g0 * comb_acc[rr][0];
            xv[rr][1] = sIn[row][l + 64] + g1 * comb_acc[rr][1];
        }
    }
    __syncthreads();
#pragma unroll
    for (int rr = 0; rr < 8; ++rr) {
        sIn[w * 8 + rr][l]      = xv[rr][0];
        sIn[w * 8 + rr][l + 64] = xv[rr][1];
    }
    __syncthreads();

    {
        int row = t >> 3, seg = t & 7;
        float s = 0.f, s2 = 0.f;
#pragma unroll
        for (int i = 0; i < 16; ++i) {
            float v = sIn[row][seg * 16 + i];
            s += v; s2 += v * v;
        }
        red[row][seg] = s;
        red2[row][seg] = s2;
    }
    __syncthreads();
    if ((t & 7) == 0) {
        int row = t >> 3;
        float ts = 0.f, ts2 = 0.f;
#pragma unroll
        for (int i = 0; i < 8; ++i) { ts += red[row][i]; ts2 += red2[row][i]; }
        float mu = ts / DIM;
        float var = ts2 / DIM - mu * mu;
        smu[row] = mu;
        srs[row] = rsqrtf(var + LN_EPS);
    }
    __syncthreads();
    {
        float gm0 = gamma[l], gm1 = gamma[l + 64];
        float bt0 = beta[l],  bt1 = beta[l + 64];
#pragma unroll
        for (int rr = 0; rr < 8; ++rr) {
            int row = w * 8 + rr;
            size_t gi = (size_t)(row0 + row) * DIM + l;
            out[gi]      = (sIn[row][l]      - smu[row]) * srs[row] * gm0 + bt0;
            out[gi + 64] = (sIn[row][l + 64] - smu[row]) * srs[row] * gm1 + bt1;
        }
    }
}

// ---------------------------------------------------------------------------
extern "C" void kernel_launch(void* const* d_in, const int* in_sizes, int n_in,
                              void* d_out, int out_size, void* d_ws, size_t ws_size,
                              hipStream_t stream) {
    const float* X     = (const float*)d_in[0];
    const float* rel   = (const float*)d_in[1];
    const int*   arows = (const int*)d_in[2];
    const int*   acols = (const int*)d_in[3];
    const float* avals = (const float*)d_in[4];
    const float* Wf    = (const float*)d_in[5];
    const float* bf    = (const float*)d_in[6];
    const float* Wr    = (const float*)d_in[7];
    const float* br    = (const float*)d_in[8];
    const float* rw    = (const float*)d_in[9];
    const float* Wg    = (const float*)d_in[10];
    const float* bg    = (const float*)d_in[11];
    const float* gamma = (const float*)d_in[12];
    const float* beta  = (const float*)d_in[13];
    float* out = (float*)d_out;

    // workspace layout (~156 MB):
    //   Yb      25.6 MB  bf16 Y = X@W1 in [2][N][64] (split) / Xb (fallback)
    //   edges   25.6 MB  bucketed (col,val) words
    //   counts   1.6 MB  CSR row starts (split) / hist counts (fallback)
    //   chunks/bfr/wsm/bcnt(padded)/bstart  small
    //   PH/PL    0.4 MB  packed hi/lo weight fragments
    //   msgs   102.4 MB  [R][N][D] bf16 relu'd messages; edges2 aliases it
    const size_t XB_B = (size_t)N_NODES * DIM * 2;
    const size_t ED_B = (size_t)NREL * NEDGE * 4;
    const size_t CT_B = (size_t)NREL * N_NODES * 4;
    char* p = (char*)d_ws;
    unsigned short* Yb     = (unsigned short*)p;  p += XB_B;
    unsigned int*   edges  = (unsigned int*)p;    p += ED_B;
    int*            counts = (int*)p;             p += CT_B;   // rowstart in split path
    int*            chunks = (int*)p;             p += 512 * 4;
    float*          bfr    = (float*)p;           p += NREL * DIM * 4;
    float*          wsm    = (float*)p;           p += 64 * 4;
    int*            bcnt   = (int*)p;             p += NREL * NBUCK * BCNT_STRIDE * 4;
    int*            bstart = (int*)p;             p += (NREL * NBUCK + 1) * 4;
    unsigned short* PH     = (unsigned short*)p;  p += 6 * 16384 * 2;
    unsigned short* PL     = (unsigned short*)p;  p += 6 * 16384 * 2;
    size_t off = (size_t)(p - (char*)d_ws);
    off = (off + 255) & ~(size_t)255;
    unsigned short* msgs = (unsigned short*)((char*)d_ws + off);
    unsigned long long* edges2 = (unsigned long long*)msgs;   // alias, pre-gather
    const size_t need = off + (size_t)NREL * N_NODES * DIM * 2;
    const bool split = (ws_size >= need);

    prep_kernel<<<1, 512, 0, stream>>>(rel, Wf, bf, rw, bfr, wsm);
    pack_kernel<<<dim3(64, 6), 256, 0, stream>>>(Wf, Wr, Wg, PH, PL);

    if (split) {
        y_kernel<<<N_NODES / 32, 256, 0, stream>>>(X, PH, PL, Yb);
        hipMemsetAsync(bcnt, 0,
                       (size_t)NREL * NBUCK * BCNT_STRIDE * sizeof(int), stream);
        const int AB = (NEDGE + P1_EDGES - 1) / P1_EDGES;   // 391
        binA_kernel<<<dim3(AB, NREL), 256, 0, stream>>>(
            arows, acols, avals, bcnt, edges2);
        bscan_kernel<<<1, 1024, 0, stream>>>(bcnt, bstart);
        binB_kernel<<<dim3(NBUCK, NREL), 256, 0, stream>>>(
            edges2, bcnt, bstart, counts, edges);
        gather_kernel<<<dim3(N_NODES / 32, NREL * 2), 256, 0, stream>>>(
            Yb, counts, edges, bfr, msgs);
        gemm2_kernel<<<N_NODES / 32, 256, 0, stream>>>(
            msgs, X, PH, PL, br, wsm, bg, gamma, beta, out);
    } else {
        xb_kernel<<<N_NODES * DIM / 4 / 256, 256, 0, stream>>>(X, Yb);
        const int EB = (NEDGE + 255) / 256;
        const int M = NREL * N_NODES;
        const int nch = (M + 1023) / 1024;
        hipMemsetAsync(counts, 0, (size_t)M * sizeof(int), stream);
        hist_kernel<<<dim3(EB, NREL), 256, 0, stream>>>(arows, counts);
        scan1_kernel<<<nch, 256, 0, stream>>>(counts, chunks, M);
        scan2_kernel<<<1, 512, 0, stream>>>(chunks, nch);
        reorder_kernel<<<dim3(EB, NREL), 256, 0, stream>>>(
            arows, acols, avals, counts, chunks, edges);
        mega_kernel<<<N_NODES / 32, 256, 0, stream>>>(
            Yb, X, counts, chunks, edges, Wf, bfr, Wr, br, wsm,
            Wg, bg, gamma, beta, out);
    }
}